// Round 6
// baseline (33.829 us; speedup 1.0000x reference)
//
#include <hip/hip_runtime.h>

// out[b,f] = x[b,f] * S. Algebraic collapse of the reference:
//   Re(factor_c) = gain_c * cos(phase_c + 0.5*D*(wl_c - mean(wl))^2) * sigmoid(aw_c)
//   S = sum_k softmax(aw)[k] * sum_c Re(factor_c) * M[c,k]
//
// Accuracy: phases ~1e5 break native-cosf f32 range reduction (R2 fail
// 2.7e-2). Reduce mod 2*pi in double ARITHMETIC only (no f64
// transcendentals), then cosf on the small argument -> absmax 2e-3.
//
// Perf history: simple loop + plain ld/st = 27.4us; nt stores = 28.5
// (force HBM writes, lose L3 write-back); 8-deep batch = 31.1 (MLP not
// needed at 32 waves/CU; hurt locality). This round: NO loop — one
// float4 per thread (16384 blocks x 256), plain cached load/store, the
// exact shape of the 6.3 TB/s copy ubench. Working set (64+64 MB) fits
// the 256 MB LLC, so plain write-back stores let L3 absorb traffic
// across graph replays.

typedef float f32x4 __attribute__((ext_vector_type(4)));

__global__ __launch_bounds__(256) void wdm_scale_kernel(
    const float* __restrict__ x,
    const float* __restrict__ gains,
    const float* __restrict__ phases,
    const float* __restrict__ aw,
    const float* __restrict__ disp,
    const float* __restrict__ ct,     // [3][3] row-major, M[c][k]
    const float* __restrict__ wl,
    float* __restrict__ out,
    int n4)                            // number of float4 elements
{
    // ---- scalar S, all-thread redundant, f64 only for phase reduction ----
    const double TWO_PI     = 6.283185307179586;
    const double INV_TWO_PI = 0.15915494309189535;

    const float w0 = wl[0], w1 = wl[1], w2 = wl[2];
    const float wlm = (w0 + w1 + w2) * (1.0f / 3.0f);
    const double D = (double)disp[0];

    const float a0 = aw[0], a1 = aw[1], a2 = aw[2];
    const float awm = fmaxf(fmaxf(a0, a1), a2);
    const float wls[3] = {w0, w1, w2};
    const float as[3]  = {a0, a1, a2};

    float re[3], ex[3];
    float sumex = 0.0f;
    #pragma unroll
    for (int c = 0; c < 3; ++c) {
        double d  = (double)wls[c] - (double)wlm;
        double ph = (double)phases[c] + 0.5 * D * d * d;
        double k = __builtin_rint(ph * INV_TWO_PI);
        float r  = (float)(ph - k * TWO_PI);
        float sg = 1.0f / (1.0f + expf(-as[c]));
        re[c] = gains[c] * cosf(r) * sg;
        ex[c] = expf(as[c] - awm);
        sumex += ex[c];
    }
    float S = 0.0f;
    #pragma unroll
    for (int k = 0; k < 3; ++k) {
        float acc = 0.0f;
        #pragma unroll
        for (int c = 0; c < 3; ++c) acc += re[c] * ct[c * 3 + k];
        S += (ex[k] / sumex) * acc;
    }

    // ---- one float4 per thread, plain cached load/store ----
    const int i = blockIdx.x * blockDim.x + threadIdx.x;
    if (i < n4) {
        const f32x4* __restrict__ x4 = (const f32x4*)x;
        f32x4* __restrict__ o4 = (f32x4*)out;
        f32x4 v = x4[i];
        v *= S;
        o4[i] = v;
    }
}

extern "C" void kernel_launch(void* const* d_in, const int* in_sizes, int n_in,
                              void* d_out, int out_size, void* d_ws, size_t ws_size,
                              hipStream_t stream) {
    const float* x      = (const float*)d_in[0];
    const float* gains  = (const float*)d_in[1];
    const float* phases = (const float*)d_in[2];
    const float* aw     = (const float*)d_in[3];
    const float* disp   = (const float*)d_in[4];
    const float* ct     = (const float*)d_in[5];
    const float* wl     = (const float*)d_in[6];
    float* out = (float*)d_out;

    int n = in_sizes[0];                // 4096*4096, divisible by 4
    int n4 = n >> 2;

    int block = 256;
    int grid = (n4 + block - 1) / block;   // 16384 for 4096x4096

    wdm_scale_kernel<<<grid, block, 0, stream>>>(x, gains, phases, aw, disp,
                                                 ct, wl, out, n4);
}

// Round 7
// 27.081 us; speedup vs baseline: 1.2492x; 1.2492x over previous
//
#include <hip/hip_runtime.h>

// out[b,f] = x[b,f] * S. Algebraic collapse of the reference:
//   Re(factor_c) = gain_c * cos(phase_c + 0.5*D*(wl_c - mean(wl))^2) * sigmoid(aw_c)
//   S = sum_k softmax(aw)[k] * sum_c Re(factor_c) * M[c,k]
//
// Accuracy: phases ~1e5 break native-cosf f32 range reduction (R2 fail
// 2.7e-2). Reduce mod 2*pi in double ARITHMETIC only (no f64
// transcendentals), then cosf on the small argument -> absmax 2e-3.
//
// Perf history (timed): R1 simple grid-stride + plain ld/st + thread0
// prologue = 27.4us (best); nt stores = 28.5 (lose LLC write-back);
// 8-deep batch = 31.1; one-f4-per-thread = 33.8 (prologue x 4.2M
// threads). This round: R1's exact loop shape (2048 blocks, sequential
// load->mul->store, cached both ways) + cheap redundant f32 prologue
// (no barrier). 128 MB working set stays LLC-resident across replays.

typedef float f32x4 __attribute__((ext_vector_type(4)));

__global__ __launch_bounds__(256) void wdm_scale_kernel(
    const float* __restrict__ x,
    const float* __restrict__ gains,
    const float* __restrict__ phases,
    const float* __restrict__ aw,
    const float* __restrict__ disp,
    const float* __restrict__ ct,     // [3][3] row-major, M[c][k]
    const float* __restrict__ wl,
    float* __restrict__ out,
    int n4)                            // number of float4 elements
{
    // ---- scalar S, all-thread redundant, f64 only for phase reduction ----
    const double TWO_PI     = 6.283185307179586;
    const double INV_TWO_PI = 0.15915494309189535;

    const float w0 = wl[0], w1 = wl[1], w2 = wl[2];
    const float wlm = (w0 + w1 + w2) * (1.0f / 3.0f);
    const double D = (double)disp[0];

    const float a0 = aw[0], a1 = aw[1], a2 = aw[2];
    const float awm = fmaxf(fmaxf(a0, a1), a2);
    const float wls[3] = {w0, w1, w2};
    const float as[3]  = {a0, a1, a2};

    float re[3], ex[3];
    float sumex = 0.0f;
    #pragma unroll
    for (int c = 0; c < 3; ++c) {
        double d  = (double)wls[c] - (double)wlm;
        double ph = (double)phases[c] + 0.5 * D * d * d;
        double k = __builtin_rint(ph * INV_TWO_PI);
        float r  = (float)(ph - k * TWO_PI);
        float sg = 1.0f / (1.0f + expf(-as[c]));
        re[c] = gains[c] * cosf(r) * sg;
        ex[c] = expf(as[c] - awm);
        sumex += ex[c];
    }
    float S = 0.0f;
    #pragma unroll
    for (int k = 0; k < 3; ++k) {
        float acc = 0.0f;
        #pragma unroll
        for (int c = 0; c < 3; ++c) acc += re[c] * ct[c * 3 + k];
        S += (ex[k] / sumex) * acc;
    }

    // ---- streaming scale: R1's simple sequential grid-stride loop ----
    const f32x4* __restrict__ x4 = (const f32x4*)x;
    f32x4* __restrict__ o4 = (f32x4*)out;

    int i = blockIdx.x * blockDim.x + threadIdx.x;
    const int stride = gridDim.x * blockDim.x;
    for (; i < n4; i += stride) {
        f32x4 v = x4[i];
        v *= S;
        o4[i] = v;
    }
}

extern "C" void kernel_launch(void* const* d_in, const int* in_sizes, int n_in,
                              void* d_out, int out_size, void* d_ws, size_t ws_size,
                              hipStream_t stream) {
    const float* x      = (const float*)d_in[0];
    const float* gains  = (const float*)d_in[1];
    const float* phases = (const float*)d_in[2];
    const float* aw     = (const float*)d_in[3];
    const float* disp   = (const float*)d_in[4];
    const float* ct     = (const float*)d_in[5];
    const float* wl     = (const float*)d_in[6];
    float* out = (float*)d_out;

    int n = in_sizes[0];                // 4096*4096, divisible by 4
    int n4 = n >> 2;

    int block = 256;
    long want = ((long)n4 + block - 1) / block;
    int grid = (int)(want < 2048 ? want : 2048);

    wdm_scale_kernel<<<grid, block, 0, stream>>>(x, gains, phases, aw, disp,
                                                 ct, wl, out, n4);
}

// Round 8
// 26.896 us; speedup vs baseline: 1.2578x; 1.0069x over previous
//
#include <hip/hip_runtime.h>

// out[b,f] = x[b,f] * S. Algebraic collapse of the reference:
//   Re(factor_c) = gain_c * cos(phase_c + 0.5*D*(wl_c - mean(wl))^2) * sigmoid(aw_c)
//   S = sum_k softmax(aw)[k] * sum_c Re(factor_c) * M[c,k]
//
// Accuracy: phases ~1e5 break native-cosf f32 range reduction (R2 fail
// 2.7e-2). Reduce mod 2*pi in double ARITHMETIC only (no f64
// transcendentals), then cosf on the small argument -> absmax 2e-3.
//
// Perf history (timed): R7 simple cached grid-stride + redundant f32
// prologue = 27.08us (best); R1 same shape + barrier prologue + scalar
// nt stores = 27.4; vector nt = 28.5; 8-batch+nt = 31.1; no-loop = 33.8.
// This round: unroll-by-2 with cached ld/st — two independent loads
// issued before the first waitcnt, breaking any load+store vmcnt(0)
// serialization, without R4's 8-wide footprint or nt stores.

typedef float f32x4 __attribute__((ext_vector_type(4)));

__global__ __launch_bounds__(256) void wdm_scale_kernel(
    const float* __restrict__ x,
    const float* __restrict__ gains,
    const float* __restrict__ phases,
    const float* __restrict__ aw,
    const float* __restrict__ disp,
    const float* __restrict__ ct,     // [3][3] row-major, M[c][k]
    const float* __restrict__ wl,
    float* __restrict__ out,
    int n4)                            // number of float4 elements
{
    // ---- scalar S, all-thread redundant, f64 only for phase reduction ----
    const double TWO_PI     = 6.283185307179586;
    const double INV_TWO_PI = 0.15915494309189535;

    const float w0 = wl[0], w1 = wl[1], w2 = wl[2];
    const float wlm = (w0 + w1 + w2) * (1.0f / 3.0f);
    const double D = (double)disp[0];

    const float a0 = aw[0], a1 = aw[1], a2 = aw[2];
    const float awm = fmaxf(fmaxf(a0, a1), a2);
    const float wls[3] = {w0, w1, w2};
    const float as[3]  = {a0, a1, a2};

    float re[3], ex[3];
    float sumex = 0.0f;
    #pragma unroll
    for (int c = 0; c < 3; ++c) {
        double d  = (double)wls[c] - (double)wlm;
        double ph = (double)phases[c] + 0.5 * D * d * d;
        double k = __builtin_rint(ph * INV_TWO_PI);
        float r  = (float)(ph - k * TWO_PI);
        float sg = 1.0f / (1.0f + expf(-as[c]));
        re[c] = gains[c] * cosf(r) * sg;
        ex[c] = expf(as[c] - awm);
        sumex += ex[c];
    }
    float S = 0.0f;
    #pragma unroll
    for (int k = 0; k < 3; ++k) {
        float acc = 0.0f;
        #pragma unroll
        for (int c = 0; c < 3; ++c) acc += re[c] * ct[c * 3 + k];
        S += (ex[k] / sumex) * acc;
    }

    // ---- streaming scale: unroll-2 grid-stride, cached both ways ----
    const f32x4* __restrict__ x4 = (const f32x4*)x;
    f32x4* __restrict__ o4 = (f32x4*)out;

    const int stride = gridDim.x * blockDim.x;
    int i = blockIdx.x * blockDim.x + threadIdx.x;
    for (; i + stride < n4; i += 2 * stride) {
        f32x4 v0 = x4[i];
        f32x4 v1 = x4[i + stride];
        v0 *= S;
        v1 *= S;
        o4[i] = v0;
        o4[i + stride] = v1;
    }
    for (; i < n4; i += stride) {
        f32x4 v = x4[i];
        v *= S;
        o4[i] = v;
    }
}

extern "C" void kernel_launch(void* const* d_in, const int* in_sizes, int n_in,
                              void* d_out, int out_size, void* d_ws, size_t ws_size,
                              hipStream_t stream) {
    const float* x      = (const float*)d_in[0];
    const float* gains  = (const float*)d_in[1];
    const float* phases = (const float*)d_in[2];
    const float* aw     = (const float*)d_in[3];
    const float* disp   = (const float*)d_in[4];
    const float* ct     = (const float*)d_in[5];
    const float* wl     = (const float*)d_in[6];
    float* out = (float*)d_out;

    int n = in_sizes[0];                // 4096*4096, divisible by 4
    int n4 = n >> 2;

    int block = 256;
    long want = ((long)n4 + block - 1) / block;
    int grid = (int)(want < 2048 ? want : 2048);

    wdm_scale_kernel<<<grid, block, 0, stream>>>(x, gains, phases, aw, disp,
                                                 ct, wl, out, n4);
}